// Round 19
// baseline (218.831 us; speedup 1.0000x reference)
//
#include <hip/hip_runtime.h>

#define BB 128
#define NN 8192
#define SS 100
#define KK 512
#define SPB 4                  // samples per block: 2 pairs, sequential
#define SPLIT (SS / SPB)       // 25 chunks per batch row
#define NT 1024                // 16 waves
#define EPT 8                  // elements per thread per sample
#define CAND 256
#define NBIN 2048
#define NWAVE 16

#define GIDX(e) (((e) >> 2) * 4096 + tid * 4 + ((e) & 3))
#define LN2 0.69314718056f

// LDS-only barrier: waits DS ops but leaves global loads in flight
// (__syncthreads drains vmcnt(0) too — guide §5). sched_barrier stops the
// compiler hoisting LDS reads above the wait (guide rule #18).
__device__ __forceinline__ void lds_barrier() {
    asm volatile("s_waitcnt lgkmcnt(0)" ::: "memory");
    __builtin_amdgcn_s_barrier();
    __builtin_amdgcn_sched_barrier(0);
}

// q-key: q = (-ln(u+eps)+eps) * e^{-lg} = e^{-p}, monotone DECREASING in p.
// ONE transcendental per element-sample; e^{-lg} computed once per block.
__device__ __forceinline__ float q_of(float u, float elg) {
    const float w = fmaf(__builtin_amdgcn_logf(u + 1e-20f), -LN2, 1e-20f);
    return w * elg;
}

// Monotone bin map via float bits (sign|exp8|mant7), flipped so HIGHER bin =
// HIGHER p. Window q in [2^-13,16) i.e. p in (-2.77, 9]; outside clamps, and
// clamped bins stay exact via the in-bin rank loop (exact q compares).
__device__ __forceinline__ int bin_of(float q) {
    const int t = (int)(__float_as_uint(q) >> 16);
    int b = 16639 - t;
    b = b < 0 ? 0 : b;
    return b > 2047 ? 2047 : b;
}

// One block = (b, 4 samples = 2 pairs processed sequentially in the SAME
// registers — live state stays 24 floats, no staging arrays (R15 lesson).
// Pair-1 loads issue after pair-0 membership; exposure covered by the
// co-resident block. 9 LDS barriers / 4 samples.
// MODE 0: packed 4-bit counts (u32/thread) -> ws. MODE 1: atomicAdd out.
template <int MODE>
__global__ __launch_bounds__(NT, 8) void gumbel_topk_kernel(
    const float* __restrict__ logits,
    const float* __restrict__ uniform,
    unsigned* __restrict__ ws,
    float* __restrict__ out) {

    __shared__ __align__(16) int histA[NBIN];
    __shared__ __align__(16) int histB[NBIN];
    __shared__ float ckA[CAND];
    __shared__ int   ciA[CAND];
    __shared__ float ckB[CAND];
    __shared__ int   ciB[CAND];
    __shared__ int waveTotA[NWAVE], waveTotB[NWAVE];
    __shared__ int bselA, bkkA, bselB, bkkB, cntA, cntB;

    const int tid  = threadIdx.x;
    const int lane = tid & 63;
    const int wv   = tid >> 6;
    const int b    = blockIdx.x / SPLIT;
    const int ch   = blockIdx.x % SPLIT;

    const float* lrow  = logits + (size_t)b * NN;
    const float* u0row = uniform + ((size_t)b * SS + ch * SPB) * NN;

    // ---- issue pair-0 + logits loads upfront; in flight across s0
    float le[EPT], qA[EPT], qB[EPT];
#pragma unroll
    for (int j = 0; j < 2; ++j) {
        *reinterpret_cast<float4*>(&qA[j * 4]) =
            *reinterpret_cast<const float4*>(&u0row[j * 4096 + tid * 4]);
        *reinterpret_cast<float4*>(&qB[j * 4]) =
            *reinterpret_cast<const float4*>(&u0row[NN + j * 4096 + tid * 4]);
        *reinterpret_cast<float4*>(&le[j * 4]) =
            *reinterpret_cast<const float4*>(&lrow[j * 4096 + tid * 4]);
    }

    // ---- init LDS: 4096 ints over 1024 threads = one int4 each
    if (tid < 512) *reinterpret_cast<int4*>(&histA[tid * 4]) = make_int4(0, 0, 0, 0);
    else           *reinterpret_cast<int4*>(&histB[(tid - 512) * 4]) = make_int4(0, 0, 0, 0);
    if (tid == 0) { cntA = 0; cntB = 0; }
    lds_barrier();                                        // s0

    // ---- le = e^{-logit} once per block (amortized over 4 samples)
#pragma unroll
    for (int e = 0; e < EPT; ++e) le[e] = __expf(-le[e]);

    unsigned cnt4 = 0;   // 4-bit membership count per element (max 4)

#pragma unroll 1
    for (int pr = 0; pr < 2; ++pr) {
        if (pr) {
            // opaque offset: stops LLVM hoisting these loads above pair-0's
            // phases into fresh registers (R15's AGPR-thrash failure mode)
            int off = 2 * NN;
            asm volatile("" : "+v"(off));
#pragma unroll
            for (int j = 0; j < 2; ++j) {
                *reinterpret_cast<float4*>(&qA[j * 4]) =
                    *reinterpret_cast<const float4*>(&u0row[off + j * 4096 + tid * 4]);
                *reinterpret_cast<float4*>(&qB[j * 4]) =
                    *reinterpret_cast<const float4*>(&u0row[off + NN + j * 4096 + tid * 4]);
            }
        }

        // ---- transform (1 log/elem) + histogram; q stays live in registers
#pragma unroll
        for (int e = 0; e < EPT; ++e) {
            qA[e] = q_of(qA[e], le[e]);
            qB[e] = q_of(qB[e], le[e]);
            atomicAdd(&histA[bin_of(qA[e])], 1);
            atomicAdd(&histB[bin_of(qB[e])], 1);
        }
        lds_barrier();                                    // s1

        // ---- scan: read own 2 bins, RE-ZERO (ready for next pair),
        // cross-wave suffix scan of both hists
        const int base = tid * 2;
        const int2 hA = *reinterpret_cast<const int2*>(&histA[base]);
        const int2 hB = *reinterpret_cast<const int2*>(&histB[base]);
        *reinterpret_cast<int2*>(&histA[base]) = make_int2(0, 0);
        *reinterpret_cast<int2*>(&histB[base]) = make_int2(0, 0);
        const int sumA = hA.x + hA.y, sumB = hB.x + hB.y;
        int sufA = sumA, sufB = sumB;
#pragma unroll
        for (int d = 1; d < 64; d <<= 1) {
            const int oA = __shfl_down(sufA, d);
            const int oB = __shfl_down(sufB, d);
            if (lane + d < 64) { sufA += oA; sufB += oB; }
        }
        if (lane == 0) { waveTotA[wv] = sufA; waveTotB[wv] = sufB; }
        lds_barrier();                                    // s2

        // ---- locate threshold bins; crossing threads broadcast; reset cnt
        // (safe: prev-pair membership readers all passed s1 already)
        int cumA = sufA - sumA, cumB = sufB - sumB;
        for (int w2 = wv + 1; w2 < NWAVE; ++w2) { cumA += waveTotA[w2]; cumB += waveTotB[w2]; }
        if (cumA < KK && cumA + hA.y >= KK) { bselA = base + 1; bkkA = KK - cumA; }
        cumA += hA.y;
        if (cumA < KK && cumA + hA.x >= KK) { bselA = base;     bkkA = KK - cumA; }
        if (cumB < KK && cumB + hB.y >= KK) { bselB = base + 1; bkkB = KK - cumB; }
        cumB += hB.y;
        if (cumB < KK && cumB + hB.x >= KK) { bselB = base;     bkkB = KK - cumB; }
        if (tid == 0) { cntA = 0; cntB = 0; }
        lds_barrier();                                    // s3

        const int selA = bselA, kkA = bkkA;
        const int selB = bselB, kkB = bkkB;

        // ---- collect threshold-bin candidates (~3/sample; keys from live q)
#pragma unroll
        for (int e = 0; e < EPT; ++e) {
            if (bin_of(qA[e]) == selA) {
                const int pos = atomicAdd(&cntA, 1);
                if (pos < CAND) { ckA[pos] = qA[e]; ciA[pos] = GIDX(e); }
            }
            if (bin_of(qB[e]) == selB) {
                const int pos = atomicAdd(&cntB, 1);
                if (pos < CAND) { ckB[pos] = qB[e]; ciB[pos] = GIDX(e); }
            }
        }
        lds_barrier();                                    // s4

        // ---- membership: in-bin elements rank by (q asc = p desc, idx asc)
        const int cA = cntA < CAND ? cntA : CAND;
        const int cB = cntB < CAND ? cntB : CAND;
#pragma unroll
        for (int e = 0; e < EPT; ++e) {
            {
                const int bb = bin_of(qA[e]);
                if (bb > selA) {
                    cnt4 += 1u << (4 * e);
                } else if (bb == selA) {
                    const float kl = qA[e]; const int il = GIDX(e);
                    int r = 0;
                    for (int j = 0; j < cA; ++j)
                        r += (ckA[j] < kl || (ckA[j] == kl && ciA[j] < il)) ? 1 : 0;
                    if (r < kkA) cnt4 += 1u << (4 * e);
                }
            }
            {
                const int bb = bin_of(qB[e]);
                if (bb > selB) {
                    cnt4 += 1u << (4 * e);
                } else if (bb == selB) {
                    const float kl = qB[e]; const int il = GIDX(e);
                    int r = 0;
                    for (int j = 0; j < cB; ++j)
                        r += (ckB[j] < kl || (ckB[j] == kl && ciB[j] < il)) ? 1 : 0;
                    if (r < kkB) cnt4 += 1u << (4 * e);
                }
            }
        }
        // no trailing barrier: next pair's hist atomics touch only hist
        // (re-zeroed in this pair's scan phase); ck/ci rewritten after next s3.
        __builtin_amdgcn_sched_barrier(0);
    }

    if (MODE == 0) {
        ws[(size_t)blockIdx.x * NT + tid] = cnt4;
    } else {
        float* orow = out + (size_t)b * NN;
#pragma unroll
        for (int e = 0; e < EPT; ++e) {
            const unsigned c = (cnt4 >> (4 * e)) & 15u;
            if (c) atomicAdd(orow + GIDX(e), (float)c * 0.01f);
        }
    }
}

// Sum 25 packed-4-bit partials per u32 position; field <= 4, sum <= 100.
__global__ __launch_bounds__(256) void reduce_kernel(
    const unsigned* __restrict__ ws, float* __restrict__ out) {
    const int g   = blockIdx.x * 256 + threadIdx.x;   // 0..131071
    const int b   = g >> 10;
    const int pos = g & 1023;
    int acc[8] = {0, 0, 0, 0, 0, 0, 0, 0};
    for (int ch = 0; ch < SPLIT; ++ch) {
        const unsigned w = ws[((size_t)(b * SPLIT + ch) << 10) + pos];
#pragma unroll
        for (int e = 0; e < 8; ++e) acc[e] += (w >> (4 * e)) & 15u;
    }
    float* ob = out + (size_t)b * NN;
    const float4 o0 = make_float4(acc[0] * 0.01f, acc[1] * 0.01f,
                                  acc[2] * 0.01f, acc[3] * 0.01f);
    const float4 o1 = make_float4(acc[4] * 0.01f, acc[5] * 0.01f,
                                  acc[6] * 0.01f, acc[7] * 0.01f);
    *reinterpret_cast<float4*>(&ob[pos * 4])        = o0;
    *reinterpret_cast<float4*>(&ob[4096 + pos * 4]) = o1;
}

extern "C" void kernel_launch(void* const* d_in, const int* in_sizes, int n_in,
                              void* d_out, int out_size, void* d_ws, size_t ws_size,
                              hipStream_t stream) {
    const float* logits  = (const float*)d_in[0];   // [128, 8192] f32
    const float* uniform = (const float*)d_in[1];   // [128, 100, 8192] f32
    float* out = (float*)d_out;                     // [128, 8192] f32

    const int grid = BB * SPLIT;                    // 3200 blocks
    const size_t cntBytes = (size_t)grid * NT * sizeof(unsigned);   // 13.1 MB

    if (ws_size >= cntBytes) {
        gumbel_topk_kernel<0><<<grid, NT, 0, stream>>>(
            logits, uniform, (unsigned*)d_ws, nullptr);
        reduce_kernel<<<(BB * NN / 8) / 256, 256, 0, stream>>>(
            (const unsigned*)d_ws, out);
    } else {
        hipMemsetAsync(out, 0, (size_t)out_size * sizeof(float), stream);
        gumbel_topk_kernel<1><<<grid, NT, 0, stream>>>(
            logits, uniform, nullptr, out);
    }
}

// Round 20
// 106.600 us; speedup vs baseline: 2.0528x; 2.0528x over previous
//
#include <hip/hip_runtime.h>

#define BB 128
#define NN 8192
#define SS 100
#define KK 512
#define SPLIT 50               // sample PAIRS per batch row (SPB=2)
#define NT 1024                // 16 waves
#define EPT 8                  // elements per thread per sample
#define CAND 256
#define NBIN 2048
#define NWAVE 16

#define GIDX(e) (((e) >> 2) * 4096 + tid * 4 + ((e) & 3))
#define LN2 0.69314718056f

// LDS-only barrier: waits DS ops but leaves global loads in flight
// (__syncthreads drains vmcnt(0) too — guide §5). sched_barrier stops the
// compiler hoisting LDS reads above the wait (guide rule #18).
__device__ __forceinline__ void lds_barrier() {
    asm volatile("s_waitcnt lgkmcnt(0)" ::: "memory");
    __builtin_amdgcn_s_barrier();
    __builtin_amdgcn_sched_barrier(0);
}

// q-key: q = (-ln(u+eps)+eps) * e^{-lg} = e^{-p}, monotone DECREASING in p.
// ONE transcendental per element-sample; e^{-lg} computed once per block
// (amortized over both samples) — bit-identical everywhere.
__device__ __forceinline__ float q_of(float u, float elg) {
    const float w = fmaf(__builtin_amdgcn_logf(u + 1e-20f), -LN2, 1e-20f);
    return w * elg;
}

// Monotone bin map via float bits (sign|exp8|mant7), flipped so HIGHER bin =
// HIGHER p. Window q in [2^-13,16) i.e. p in (-2.77, 9]; outside clamps, and
// clamped bins stay exact via the in-bin rank loop (exact q compares).
__device__ __forceinline__ int bin_of(float q) {
    const int t = (int)(__float_as_uint(q) >> 16);
    int b = 16639 - t;
    b = b < 0 ? 0 : b;
    return b > 2047 ? 2047 : b;
}

// One block = (b, pair of samples). 5 LDS barriers; global loads are never
// drained by a barrier. R14 structure with exp fused (no precompute pass).
// MODE 0: packed 2-bit counts (u16/thread) -> ws. MODE 1: atomicAdd out.
template <int MODE>
__global__ __launch_bounds__(NT, 8) void gumbel_topk_kernel(
    const float* __restrict__ logits,
    const float* __restrict__ uniform,
    unsigned short* __restrict__ ws,
    float* __restrict__ out) {

    __shared__ __align__(16) int histA[NBIN];
    __shared__ __align__(16) int histB[NBIN];
    __shared__ float ckA[CAND];
    __shared__ int   ciA[CAND];
    __shared__ float ckB[CAND];
    __shared__ int   ciB[CAND];
    __shared__ int waveTotA[NWAVE], waveTotB[NWAVE];
    __shared__ int bselA, bkkA, bselB, bkkB, cntA, cntB;

    const int tid  = threadIdx.x;
    const int lane = tid & 63;
    const int wv   = tid >> 6;
    const int b    = blockIdx.x / SPLIT;
    const int ch   = blockIdx.x % SPLIT;

    const float* lrow  = logits + (size_t)b * NN;
    const float* uArow = uniform + ((size_t)b * SS + ch * 2) * NN;
    const float* uBrow = uArow + NN;

    // ---- issue ALL global loads upfront; they stay in flight across s0
    float le[EPT], qA[EPT], qB[EPT];
#pragma unroll
    for (int j = 0; j < 2; ++j) {
        *reinterpret_cast<float4*>(&qA[j * 4]) =
            *reinterpret_cast<const float4*>(&uArow[j * 4096 + tid * 4]);
        *reinterpret_cast<float4*>(&qB[j * 4]) =
            *reinterpret_cast<const float4*>(&uBrow[j * 4096 + tid * 4]);
        *reinterpret_cast<float4*>(&le[j * 4]) =
            *reinterpret_cast<const float4*>(&lrow[j * 4096 + tid * 4]);
    }

    // ---- init LDS: 4096 ints over 1024 threads = one int4 each
    if (tid < 512) *reinterpret_cast<int4*>(&histA[tid * 4]) = make_int4(0, 0, 0, 0);
    else           *reinterpret_cast<int4*>(&histB[(tid - 512) * 4]) = make_int4(0, 0, 0, 0);
    if (tid == 0) { cntA = 0; cntB = 0; }
    lds_barrier();                                        // s0

    // ---- le = e^{-logit} (once per block; vmcnt waits happen here at use)
#pragma unroll
    for (int e = 0; e < EPT; ++e) le[e] = __expf(-le[e]);

    // ---- transform (1 log/elem) + histogram; q stays live in registers
#pragma unroll
    for (int e = 0; e < EPT; ++e) {
        qA[e] = q_of(qA[e], le[e]);
        qB[e] = q_of(qB[e], le[e]);
        atomicAdd(&histA[bin_of(qA[e])], 1);
        atomicAdd(&histB[bin_of(qB[e])], 1);
    }
    lds_barrier();                                        // s1

    // ---- cross-wave suffix scan of both hists (2 bins/thread); the
    // crossing thread broadcasts (sel, kk). 2 barriers.
    {
        const int base = tid * 2;
        const int2 hA = *reinterpret_cast<const int2*>(&histA[base]);
        const int2 hB = *reinterpret_cast<const int2*>(&histB[base]);
        const int sumA = hA.x + hA.y, sumB = hB.x + hB.y;
        int sufA = sumA, sufB = sumB;
#pragma unroll
        for (int d = 1; d < 64; d <<= 1) {
            const int oA = __shfl_down(sufA, d);
            const int oB = __shfl_down(sufB, d);
            if (lane + d < 64) { sufA += oA; sufB += oB; }
        }
        if (lane == 0) { waveTotA[wv] = sufA; waveTotB[wv] = sufB; }
        lds_barrier();                                    // s2
        int cumA = sufA - sumA, cumB = sufB - sumB;
        for (int w2 = wv + 1; w2 < NWAVE; ++w2) { cumA += waveTotA[w2]; cumB += waveTotB[w2]; }
        if (cumA < KK && cumA + hA.y >= KK) { bselA = base + 1; bkkA = KK - cumA; }
        cumA += hA.y;
        if (cumA < KK && cumA + hA.x >= KK) { bselA = base;     bkkA = KK - cumA; }
        if (cumB < KK && cumB + hB.y >= KK) { bselB = base + 1; bkkB = KK - cumB; }
        cumB += hB.y;
        if (cumB < KK && cumB + hB.x >= KK) { bselB = base;     bkkB = KK - cumB; }
        lds_barrier();                                    // s3
    }

    const int selA = bselA, kkA = bkkA;
    const int selB = bselB, kkB = bkkB;

    // ---- collect threshold-bin candidates (~3/sample; keys from live q)
#pragma unroll
    for (int e = 0; e < EPT; ++e) {
        if (bin_of(qA[e]) == selA) {
            const int pos = atomicAdd(&cntA, 1);
            if (pos < CAND) { ckA[pos] = qA[e]; ciA[pos] = GIDX(e); }
        }
        if (bin_of(qB[e]) == selB) {
            const int pos = atomicAdd(&cntB, 1);
            if (pos < CAND) { ckB[pos] = qB[e]; ciB[pos] = GIDX(e); }
        }
    }
    lds_barrier();                                        // s4

    // ---- membership: 2-bit count per element; in-bin elements rank by
    // (q asc = p desc, idx asc) — JAX tie-break.
    const int cA = cntA < CAND ? cntA : CAND;
    const int cB = cntB < CAND ? cntB : CAND;
    unsigned cnt8 = 0;
#pragma unroll
    for (int e = 0; e < EPT; ++e) {
        {
            const int bb = bin_of(qA[e]);
            if (bb > selA) {
                cnt8 += 1u << (2 * e);
            } else if (bb == selA) {
                const float kl = qA[e]; const int il = GIDX(e);
                int r = 0;
                for (int j = 0; j < cA; ++j)
                    r += (ckA[j] < kl || (ckA[j] == kl && ciA[j] < il)) ? 1 : 0;
                if (r < kkA) cnt8 += 1u << (2 * e);
            }
        }
        {
            const int bb = bin_of(qB[e]);
            if (bb > selB) {
                cnt8 += 1u << (2 * e);
            } else if (bb == selB) {
                const float kl = qB[e]; const int il = GIDX(e);
                int r = 0;
                for (int j = 0; j < cB; ++j)
                    r += (ckB[j] < kl || (ckB[j] == kl && ciB[j] < il)) ? 1 : 0;
                if (r < kkB) cnt8 += 1u << (2 * e);
            }
        }
    }

    if (MODE == 0) {
        ws[(size_t)blockIdx.x * NT + tid] = (unsigned short)cnt8;
    } else {
        float* orow = out + (size_t)b * NN;
#pragma unroll
        for (int e = 0; e < EPT; ++e) {
            const unsigned c = (cnt8 >> (2 * e)) & 3u;
            if (c) atomicAdd(orow + GIDX(e), (float)c * 0.01f);
        }
    }
}

// Sum 50 packed-2-bit partials per u16 position; each field <= 2, sum <= 100.
__global__ __launch_bounds__(256) void reduce_kernel(
    const unsigned short* __restrict__ ws, float* __restrict__ out) {
    const int g   = blockIdx.x * 256 + threadIdx.x;   // 0..131071
    const int b   = g >> 10;
    const int pos = g & 1023;
    int acc[8] = {0, 0, 0, 0, 0, 0, 0, 0};
    for (int ch = 0; ch < SPLIT; ++ch) {
        const unsigned w = ws[((size_t)(b * SPLIT + ch) << 10) + pos];
#pragma unroll
        for (int e = 0; e < 8; ++e) acc[e] += (w >> (2 * e)) & 3u;
    }
    float* ob = out + (size_t)b * NN;
    const float4 o0 = make_float4(acc[0] * 0.01f, acc[1] * 0.01f,
                                  acc[2] * 0.01f, acc[3] * 0.01f);
    const float4 o1 = make_float4(acc[4] * 0.01f, acc[5] * 0.01f,
                                  acc[6] * 0.01f, acc[7] * 0.01f);
    *reinterpret_cast<float4*>(&ob[pos * 4])        = o0;
    *reinterpret_cast<float4*>(&ob[4096 + pos * 4]) = o1;
}

extern "C" void kernel_launch(void* const* d_in, const int* in_sizes, int n_in,
                              void* d_out, int out_size, void* d_ws, size_t ws_size,
                              hipStream_t stream) {
    const float* logits  = (const float*)d_in[0];   // [128, 8192] f32
    const float* uniform = (const float*)d_in[1];   // [128, 100, 8192] f32
    float* out = (float*)d_out;                     // [128, 8192] f32

    const int grid = BB * SPLIT;                    // 6400 blocks
    const size_t cntBytes = (size_t)grid * NT * sizeof(unsigned short); // 13 MB

    if (ws_size >= cntBytes) {
        gumbel_topk_kernel<0><<<grid, NT, 0, stream>>>(
            logits, uniform, (unsigned short*)d_ws, nullptr);
        reduce_kernel<<<(BB * NN / 8) / 256, 256, 0, stream>>>(
            (const unsigned short*)d_ws, out);
    } else {
        hipMemsetAsync(out, 0, (size_t)out_size * sizeof(float), stream);
        gumbel_topk_kernel<1><<<grid, NT, 0, stream>>>(
            logits, uniform, nullptr, out);
    }
}